// Round 5
// baseline (681.680 us; speedup 1.0000x reference)
//
#include <hip/hip_runtime.h>
#include <hip/hip_bf16.h>
#include <stdint.h>

typedef __hip_bfloat16 bf16;
typedef __attribute__((ext_vector_type(8))) short short8;
typedef __attribute__((ext_vector_type(4))) float f32x4;

#define BM 128
#define BN 128

__device__ __forceinline__ unsigned short f2bf_bits(float x) {
    return __builtin_bit_cast(unsigned short, __float2bfloat16(x));
}

// async global->LDS, 16B per lane, LDS dest = wave-uniform base + lane*16
__device__ __forceinline__ void gload_lds16(const bf16* g, bf16* l) {
    __builtin_amdgcn_global_load_lds(
        (const __attribute__((address_space(1))) void*)(const void*)g,
        (__attribute__((address_space(3))) void*)(void*)l,
        16, 0, 0);
}

// fused prep: [0,8192) feat->bf16 cvt; [8192,11264) W transpose+cvt; [11264] zero lsum
__global__ void prep_kernel(const float* __restrict__ feat, unsigned short* __restrict__ featb,
                            const float* __restrict__ W0, const float* __restrict__ W1,
                            const float* __restrict__ W2, bf16* __restrict__ Wt,
                            float* __restrict__ lsum) {
    const int b = blockIdx.x;
    const int tid = threadIdx.x;
    if (b < 8192) {
        int i = b * 256 + tid;
        float4 v = reinterpret_cast<const float4*>(feat)[i];
        ushort4 o;
        o.x = f2bf_bits(v.x); o.y = f2bf_bits(v.y);
        o.z = f2bf_bits(v.z); o.w = f2bf_bits(v.w);
        reinterpret_cast<ushort4*>(featb)[i] = o;
    } else if (b < 11264) {
        __shared__ float tile[32][33];
        const int b2 = b - 8192;
        const int z = b2 >> 10;
        const int t = b2 & 1023;
        const int bx = t & 31, by = t >> 5;
        const int tx = tid & 31, ty = tid >> 5;
        const float* in = (z == 0) ? W0 : (z == 1) ? W1 : W2;
        bf16* out = Wt + (size_t)z * 1024 * 1024;
        for (int r = ty; r < 32; r += 8)
            tile[r][tx] = in[(size_t)(by * 32 + r) * 1024 + bx * 32 + tx];
        __syncthreads();
        for (int r = ty; r < 32; r += 8)
            out[(size_t)(bx * 32 + r) * 1024 + by * 32 + tx] = __float2bfloat16(tile[tx][r]);
    } else {
        for (int i = tid; i < 8192; i += 256) lsum[i] = 0.f;
    }
}

__global__ void scale_rows(float* __restrict__ out, const float* __restrict__ lsum) {
    int i = blockIdx.x * 256 + threadIdx.x;
    float4 v = reinterpret_cast<float4*>(out)[i];
    float inv = 1.0f / lsum[i >> 8];
    v.x *= inv; v.y *= inv; v.z *= inv; v.w *= inv;
    reinterpret_cast<float4*>(out)[i] = v;
}

// ---------------------------------------------------------------------------
// gemm_bt: proven 128x128 2-barrier structure.
// Used for projections (MODE 0) and the chunked fallback (MODE 1/2).
// ---------------------------------------------------------------------------
template <int MODE, int KH, int SWAP>
__global__ __launch_bounds__(256, 4)
void gemm_bt(const bf16* __restrict__ A, const bf16* __restrict__ B,
             const float* __restrict__ b0, const float* __restrict__ b1,
             const float* __restrict__ b2, float* __restrict__ lsum,
             bf16* __restrict__ outb, float* __restrict__ outf,
             int M, int N, int K, int ldb, int ldout, float scale) {
    constexpr int TILE = 128 * 32;
    constexpr int SELEMS = (2 * KH * TILE < 9216) ? 9216 : 2 * KH * TILE;
    __shared__ bf16 smem[SELEMS];
    bf16* As = smem;
    bf16* Bs = smem + KH * TILE;

    const int tid  = threadIdx.x;
    const int lane = tid & 63;
    const int wave = tid >> 6;
    const int wm = wave & 1, wn = wave >> 1;
    const int l16  = lane & 15;
    const int quad = lane >> 4;
    long bm0, bn0;
    if (SWAP == 2) {
        const int lin = blockIdx.y * 8 + blockIdx.x;
        const int xcd = lin & 7;
        const int s   = lin >> 3;
        bn0 = (long)(s & 7) * BN;
        bm0 = (long)((s >> 3) * 8 + xcd) * BM;
    } else {
        bm0 = (long)(SWAP ? blockIdx.y : blockIdx.x) * BM;
        bn0 = (long)(SWAP ? blockIdx.x : blockIdx.y) * BN;
    }

    const bf16* Ause = A;
    const bf16* Buse = B;
    bf16* oz = outb;
    int  ldo = ldout;
    int  z   = 0;
    if (MODE == 0) {
        z = blockIdx.z;
        if (z == 2) {
            bm0  = (long)blockIdx.y * BM;
            bn0  = (long)blockIdx.x * BN;
            Ause = B + (size_t)2 * N * K;
            Buse = A;
            oz   = outb + (size_t)2 * M * ldout;
            ldo  = M;
        } else {
            Buse = B + (size_t)z * N * K;
            oz   = outb + (size_t)z * M * ldout;
        }
    }

    const int lrow = lane >> 2;
    const int lcol = (lane & 3) * 8;
    const bf16* gA[2][KH];
    const bf16* gB[2][KH];
    bf16* lA[2][KH];
    bf16* lB[2][KH];
#pragma unroll
    for (int u = 0; u < 2; u++)
#pragma unroll
        for (int h = 0; h < KH; h++) {
            gA[u][h] = Ause + (size_t)(bm0 + wave * 32 + u * 16 + lrow) * K + h * 32 + lcol;
            gB[u][h] = Buse + (size_t)(bn0 + wave * 32 + u * 16 + lrow) * ldb + h * 32 + lcol;
            lA[u][h] = As + h * TILE + (wave * 32 + u * 16) * 32;
            lB[u][h] = Bs + h * TILE + (wave * 32 + u * 16) * 32;
        }

    const bf16* Ard = As + (wm * 64 + l16) * 32 + quad * 8;
    const bf16* Brd = Bs + (wn * 64 + l16) * 32 + quad * 8;

    f32x4 acc[4][4];
    const f32x4 zero = {0.f, 0.f, 0.f, 0.f};
#pragma unroll
    for (int i = 0; i < 4; i++)
#pragma unroll
        for (int j = 0; j < 4; j++) acc[i][j] = zero;

    for (int k0 = 0; k0 < K; k0 += KH * 32) {
        __syncthreads();
#pragma unroll
        for (int u = 0; u < 2; u++)
#pragma unroll
            for (int h = 0; h < KH; h++) {
                gload_lds16(gA[u][h] + k0, lA[u][h]);
                gload_lds16(gB[u][h] + k0, lB[u][h]);
            }
        __syncthreads();
#pragma unroll
        for (int h = 0; h < KH; h++) {
            short8 af[4], bfr[4];
#pragma unroll
            for (int mi = 0; mi < 4; mi++)
                af[mi] = *reinterpret_cast<const short8*>(Ard + h * TILE + mi * 16 * 32);
#pragma unroll
            for (int ni = 0; ni < 4; ni++)
                bfr[ni] = *reinterpret_cast<const short8*>(Brd + h * TILE + ni * 16 * 32);
#pragma unroll
            for (int mi = 0; mi < 4; mi++)
#pragma unroll
                for (int ni = 0; ni < 4; ni++)
                    acc[mi][ni] = __builtin_amdgcn_mfma_f32_16x16x32_bf16(af[mi], bfr[ni], acc[mi][ni], 0, 0, 0);
        }
    }

    if (MODE == 0 || MODE == 1) {
        __syncthreads();
        float bcol[4];
        if (MODE == 0 && z < 2) {
            const float* bias = (z == 0) ? b0 : b1;
#pragma unroll
            for (int ni = 0; ni < 4; ni++) bcol[ni] = bias[bn0 + wn * 64 + l16 + ni * 16];
        }
#pragma unroll
        for (int mi = 0; mi < 4; mi++) {
            bf16* eb = smem + ((wave << 1) | (mi & 1)) * 1152;
#pragma unroll
            for (int r = 0; r < 4; r++) {
                float s = 0.f;
                float brow = 0.f;
                if (MODE == 0 && z == 2) brow = b2[bm0 + wm * 64 + mi * 16 + quad * 4 + r];
#pragma unroll
                for (int ni = 0; ni < 4; ni++) {
                    float v = acc[mi][ni][r];
                    if (MODE == 0) v += (z == 2) ? brow : bcol[ni];
                    else { v = __expf(v * scale); s += v; }
                    eb[(quad * 4 + r) * 72 + ni * 16 + l16] = __float2bfloat16(v);
                }
                if (MODE == 1) {
                    s += __shfl_xor(s, 1);
                    s += __shfl_xor(s, 2);
                    s += __shfl_xor(s, 4);
                    s += __shfl_xor(s, 8);
                    if (l16 == 0) atomicAdd(&lsum[bm0 + wm * 64 + mi * 16 + quad * 4 + r], s);
                }
            }
            asm volatile("s_waitcnt lgkmcnt(0)" ::: "memory");
#pragma unroll
            for (int p = 0; p < 2; p++) {
                int r2 = p * 8 + (lane >> 3);
                int c2 = (lane & 7) * 8;
                short8 val = *reinterpret_cast<const short8*>(eb + r2 * 72 + c2);
                *reinterpret_cast<short8*>(
                    oz + (size_t)(bm0 + wm * 64 + mi * 16 + r2) * ldo + bn0 + wn * 64 + c2) = val;
            }
        }
    } else {
        const int rb2 = wm * 64 + quad * 4;
        const int cb2 = wn * 64 + l16;
#pragma unroll
        for (int mi = 0; mi < 4; mi++)
#pragma unroll
            for (int r = 0; r < 4; r++) {
                long row = bm0 + rb2 + mi * 16 + r;
                float mul = (MODE == 3) ? 1.0f / lsum[row] : 0.f;
#pragma unroll
                for (int ni = 0; ni < 4; ni++) {
                    long col = bn0 + cb2 + ni * 16;
                    if (MODE == 3) outf[row * ldout + col] = acc[mi][ni][r] * mul;
                    else           outf[row * ldout + col] += acc[mi][ni][r];
                }
            }
    }
}

// ---------------------------------------------------------------------------
// gemm_bg: 128x128 tile, A double-buffered in LDS (2 x 16 KiB), B-fragments
// read DIRECTLY from global (L2-resident slab), ONE barrier per K-step.
// Rationale (m233/r4 counters): the 2-sync structure's critical path is
// stage->vmcnt-drain->barrier (~72%), not MFMA and not LDS conflicts
// (r4: conflicts -25x, perf -29%).  Halving staged bytes (A only) and
// removing one barrier directly shrinks that segment; B global loads are
// compiler-pipelined per-lane 16B loads with no barrier coupling.
// MODE 1: P = exp(C*scale) -> bf16 + lsum atomics (QK).  SWAP=0 grid.
// MODE 3: out = C / lsum[row] (PV).  SWAP=2 XCD grid: col-tile == XCD,
//         so each XCD's V slab (128 x 8192 x 2B = 2 MB) stays in its L2.
// ---------------------------------------------------------------------------
template <int MODE, int SWAP>
__global__ __launch_bounds__(256, 2)
void gemm_bg(const bf16* __restrict__ A, const bf16* __restrict__ B,
             float* __restrict__ lsum, bf16* __restrict__ outb,
             float* __restrict__ outf, int M, int N, int K,
             int ldb, int ldout, float scale) {
    constexpr int TILE = 128 * 32;          // one BK=32 half of the A tile
    __shared__ bf16 smem[2 * 2 * TILE];     // 2 bufs x (KH=2 halves) = 32 KiB

    const int tid  = threadIdx.x;
    const int lane = tid & 63;
    const int wave = tid >> 6;
    const int wm = wave & 1, wn = wave >> 1;
    const int l16  = lane & 15;
    const int quad = lane >> 4;
    long bm0, bn0;
    if (SWAP == 2) {
        const int lin = blockIdx.y * 8 + blockIdx.x;  // x fastest in dispatch
        const int xcd = lin & 7;
        const int s   = lin >> 3;
        bn0 = (long)(s & 7) * BN;               // col tile == XCD
        bm0 = (long)((s >> 3) * 8 + xcd) * BM;
    } else {
        bm0 = (long)blockIdx.x * BM;
        bn0 = (long)blockIdx.y * BN;
    }

    // A staging (per buf): 2u x 2h gload_lds16, rows [wave*32, +32)
    const int lrow = lane >> 2;
    const int lcol = (lane & 3) * 8;
    const bf16* gA[2][2];
    int lA[2][2];
#pragma unroll
    for (int u = 0; u < 2; u++)
#pragma unroll
        for (int h = 0; h < 2; h++) {
            gA[u][h] = A + (size_t)(bm0 + wave * 32 + u * 16 + lrow) * K + h * 32 + lcol;
            lA[u][h] = h * TILE + (wave * 32 + u * 16) * 32;
        }

    const int ardo = (wm * 64 + l16) * 32 + quad * 8;
    // B fragment global base: row = bn0 + wn*64 + ni*16 + l16, col = quad*8
    const bf16* gBf[4];
#pragma unroll
    for (int ni = 0; ni < 4; ni++)
        gBf[ni] = B + (size_t)(bn0 + wn * 64 + ni * 16 + l16) * ldb + quad * 8;

    f32x4 acc[4][4];
    const f32x4 zero = {0.f, 0.f, 0.f, 0.f};
#pragma unroll
    for (int i = 0; i < 4; i++)
#pragma unroll
        for (int j = 0; j < 4; j++) acc[i][j] = zero;

    auto stageA = [&](int buf, int k0) {
        bf16* dst = smem + buf * 2 * TILE;
#pragma unroll
        for (int u = 0; u < 2; u++)
#pragma unroll
            for (int h = 0; h < 2; h++)
                gload_lds16(gA[u][h] + k0, dst + lA[u][h]);
    };

    stageA(0, 0);
    __syncthreads();   // drains vmcnt(0): buf0 resident

    const int NS = K / 64;
    for (int s = 0; s < NS; ++s) {
        const int k0 = s * 64;
        const bf16* Ard = smem + (s & 1) * 2 * TILE + ardo;
        if (s + 1 < NS) stageA((s + 1) & 1, k0 + 64);
#pragma unroll
        for (int h = 0; h < 2; h++) {
            short8 af[4], bfr[4];
#pragma unroll
            for (int ni = 0; ni < 4; ni++)
                bfr[ni] = *reinterpret_cast<const short8*>(gBf[ni] + k0 + h * 32);
#pragma unroll
            for (int mi = 0; mi < 4; mi++)
                af[mi] = *reinterpret_cast<const short8*>(Ard + h * TILE + mi * 16 * 32);
#pragma unroll
            for (int mi = 0; mi < 4; mi++)
#pragma unroll
                for (int ni = 0; ni < 4; ni++)
                    acc[mi][ni] = __builtin_amdgcn_mfma_f32_16x16x32_bf16(af[mi], bfr[ni], acc[mi][ni], 0, 0, 0);
        }
        __syncthreads();  // next-buf staged (vmcnt 0) + all reads of cur done
    }

    // epilogues verbatim from gemm_bt
    if constexpr (MODE == 1) {
#pragma unroll
        for (int mi = 0; mi < 4; mi++) {
            bf16* eb = smem + ((wave << 1) | (mi & 1)) * 1152;
#pragma unroll
            for (int r = 0; r < 4; r++) {
                float s = 0.f;
#pragma unroll
                for (int ni = 0; ni < 4; ni++) {
                    float v = __expf(acc[mi][ni][r] * scale);
                    s += v;
                    eb[(quad * 4 + r) * 72 + ni * 16 + l16] = __float2bfloat16(v);
                }
                s += __shfl_xor(s, 1);
                s += __shfl_xor(s, 2);
                s += __shfl_xor(s, 4);
                s += __shfl_xor(s, 8);
                if (l16 == 0) atomicAdd(&lsum[bm0 + wm * 64 + mi * 16 + quad * 4 + r], s);
            }
            asm volatile("s_waitcnt lgkmcnt(0)" ::: "memory");
#pragma unroll
            for (int p = 0; p < 2; p++) {
                int r2 = p * 8 + (lane >> 3);
                int c2 = (lane & 7) * 8;
                short8 val = *reinterpret_cast<const short8*>(eb + r2 * 72 + c2);
                *reinterpret_cast<short8*>(
                    outb + (size_t)(bm0 + wm * 64 + mi * 16 + r2) * ldout + bn0 + wn * 64 + c2) = val;
            }
        }
    } else {
        const int rb2 = wm * 64 + quad * 4;
        const int cb2 = wn * 64 + l16;
#pragma unroll
        for (int mi = 0; mi < 4; mi++)
#pragma unroll
            for (int r = 0; r < 4; r++) {
                long row = bm0 + rb2 + mi * 16 + r;
                float mul = 1.0f / lsum[row];
#pragma unroll
                for (int ni = 0; ni < 4; ni++) {
                    long col = bn0 + cb2 + ni * 16;
                    outf[row * ldout + col] = acc[mi][ni][r] * mul;
                }
            }
    }
}

extern "C" void kernel_launch(void* const* d_in, const int* in_sizes, int n_in,
                              void* d_out, int out_size, void* d_ws, size_t ws_size,
                              hipStream_t stream) {
    const float* feat = (const float*)d_in[0];
    const float* Wq   = (const float*)d_in[1];
    const float* bqv  = (const float*)d_in[2];
    const float* Wk   = (const float*)d_in[3];
    const float* bkv  = (const float*)d_in[4];
    const float* Wv   = (const float*)d_in[5];
    const float* bvv  = (const float*)d_in[6];
    float* outp = (float*)d_out;

    const int M = 8192, D = 1024;
    char* ws = (char*)d_ws;
    size_t off = 0;
    auto carve = [&](size_t bytes) -> char* {
        char* r = ws + off;
        off += (bytes + 255) & ~(size_t)255;
        return r;
    };
    bf16* featb = (bf16*)carve((size_t)M * D * 2);
    bf16* Wbt   = (bf16*)carve((size_t)3 * D * D * 2);
    bf16* qk    = (bf16*)carve((size_t)2 * M * D * 2 + (size_t)D * M * 2);
    bf16* vbt   = qk + (size_t)2 * M * D;
    float* lsum = (float*)carve((size_t)M * 4);
    size_t avail = (ws_size > off) ? ws_size - off : 0;

    int C;  // key-chunk width for P
    if      (avail >= (size_t)M * M * 2)    C = M;     // full P, 128 MB
    else if (avail >= (size_t)M * 4096 * 2) C = 4096;
    else if (avail >= (size_t)M * 2048 * 2) C = 2048;
    else                                    C = 1024;
    bf16* Pc = (bf16*)carve((size_t)M * C * 2);

    // 1) fused prep: feat->bf16, W transpose+cvt, lsum zero
    prep_kernel<<<dim3(11265), dim3(256), 0, stream>>>(
        feat, (unsigned short*)featb, Wq, Wk, Wv, Wbt, lsum);
    // 2) merged projection: z=0,1 -> q,k; z=2 -> v^T directly (BK=64)
    gemm_bt<0, 2, 0><<<dim3(M / 128, D / 128, 3), dim3(256), 0, stream>>>(
        featb, Wbt, bqv, bkv, bvv, nullptr, qk, nullptr, M, D, D, D, D, 1.0f);

    const float scale = 0.03125f;  // 1/sqrt(1024)
    bf16* qb = qk;
    bf16* kb = qk + (size_t)M * D;
    if (C == M) {
        // 3a) P = exp(q k^T/32): A-dbuf + B-from-global, 1 barrier/K-step
        gemm_bg<1, 0><<<dim3(M / 128, M / 128), dim3(256), 0, stream>>>(
            qb, kb, lsum, Pc, nullptr, M, M, D, D, M, scale);
        // 4a) out = (P v^T)/lsum: same structure, K=8192, XCD grid (V in L2)
        gemm_bg<3, 2><<<dim3(8, M / 128), dim3(256), 0, stream>>>(
            Pc, vbt, lsum, nullptr, outp, M, D, M, M, D, 0.f);
    } else {
        hipMemsetAsync(outp, 0, (size_t)M * D * 4, stream);
        for (int c = 0; c < M / C; c++) {
            gemm_bt<1, 2, 0><<<dim3(M / 128, C / 128), dim3(256), 0, stream>>>(
                qb, kb + (size_t)c * C * D, nullptr, nullptr, nullptr, lsum, Pc, nullptr,
                M, C, D, D, C, scale);
            gemm_bt<2, 2, 1><<<dim3(D / 128, M / 128), dim3(256), 0, stream>>>(
                Pc, vbt + (size_t)c * C, nullptr, nullptr, nullptr, nullptr, nullptr, outp,
                M, D, C, M, D, 0.f);
        }
        scale_rows<<<dim3(M * D / 4 / 256), dim3(256), 0, stream>>>(outp, lsum);
    }
}

// Round 6
// 441.856 us; speedup vs baseline: 1.5428x; 1.5428x over previous
//
#include <hip/hip_runtime.h>
#include <hip/hip_bf16.h>
#include <stdint.h>

typedef __hip_bfloat16 bf16;
typedef __attribute__((ext_vector_type(8))) short short8;
typedef __attribute__((ext_vector_type(4))) float f32x4;

#define BM 128
#define BN 128

__device__ __forceinline__ unsigned short f2bf_bits(float x) {
    return __builtin_bit_cast(unsigned short, __float2bfloat16(x));
}

// async global->LDS, 16B per lane, LDS dest = wave-uniform base + lane*16
__device__ __forceinline__ void gload_lds16(const bf16* g, bf16* l) {
    __builtin_amdgcn_global_load_lds(
        (const __attribute__((address_space(1))) void*)(const void*)g,
        (__attribute__((address_space(3))) void*)(void*)l,
        16, 0, 0);
}

template <int N>
__device__ __forceinline__ void waitvm() {
    if constexpr (N == 0) asm volatile("s_waitcnt vmcnt(0)" ::: "memory");
    else if constexpr (N == 6) asm volatile("s_waitcnt vmcnt(6)" ::: "memory");
}

// fused prep: [0,8192) feat->bf16 cvt; [8192,11264) W transpose+cvt; [11264] zero lsum
__global__ void prep_kernel(const float* __restrict__ feat, unsigned short* __restrict__ featb,
                            const float* __restrict__ W0, const float* __restrict__ W1,
                            const float* __restrict__ W2, bf16* __restrict__ Wt,
                            float* __restrict__ lsum) {
    const int b = blockIdx.x;
    const int tid = threadIdx.x;
    if (b < 8192) {
        int i = b * 256 + tid;
        float4 v = reinterpret_cast<const float4*>(feat)[i];
        ushort4 o;
        o.x = f2bf_bits(v.x); o.y = f2bf_bits(v.y);
        o.z = f2bf_bits(v.z); o.w = f2bf_bits(v.w);
        reinterpret_cast<ushort4*>(featb)[i] = o;
    } else if (b < 11264) {
        __shared__ float tile[32][33];
        const int b2 = b - 8192;
        const int z = b2 >> 10;
        const int t = b2 & 1023;
        const int bx = t & 31, by = t >> 5;
        const int tx = tid & 31, ty = tid >> 5;
        const float* in = (z == 0) ? W0 : (z == 1) ? W1 : W2;
        bf16* out = Wt + (size_t)z * 1024 * 1024;
        for (int r = ty; r < 32; r += 8)
            tile[r][tx] = in[(size_t)(by * 32 + r) * 1024 + bx * 32 + tx];
        __syncthreads();
        for (int r = ty; r < 32; r += 8)
            out[(size_t)(bx * 32 + r) * 1024 + by * 32 + tx] = __float2bfloat16(tile[tx][r]);
    } else {
        for (int i = tid; i < 8192; i += 256) lsum[i] = 0.f;
    }
}

__global__ void scale_rows(float* __restrict__ out, const float* __restrict__ lsum) {
    int i = blockIdx.x * 256 + threadIdx.x;
    float4 v = reinterpret_cast<float4*>(out)[i];
    float inv = 1.0f / lsum[i >> 8];
    v.x *= inv; v.y *= inv; v.z *= inv; v.w *= inv;
    reinterpret_cast<float4*>(out)[i] = v;
}

// ---------------------------------------------------------------------------
// gemm_bt: proven 128x128 2-barrier structure (baseline).  Projections
// (MODE 0), QK (MODE 1), PV fallback (MODE 2/3).
// ---------------------------------------------------------------------------
template <int MODE, int KH, int SWAP>
__global__ __launch_bounds__(256, 4)
void gemm_bt(const bf16* __restrict__ A, const bf16* __restrict__ B,
             const float* __restrict__ b0, const float* __restrict__ b1,
             const float* __restrict__ b2, float* __restrict__ lsum,
             bf16* __restrict__ outb, float* __restrict__ outf,
             int M, int N, int K, int ldb, int ldout, float scale) {
    constexpr int TILE = 128 * 32;
    constexpr int SELEMS = (2 * KH * TILE < 9216) ? 9216 : 2 * KH * TILE;
    __shared__ bf16 smem[SELEMS];
    bf16* As = smem;
    bf16* Bs = smem + KH * TILE;

    const int tid  = threadIdx.x;
    const int lane = tid & 63;
    const int wave = tid >> 6;
    const int wm = wave & 1, wn = wave >> 1;
    const int l16  = lane & 15;
    const int quad = lane >> 4;
    long bm0, bn0;
    if (SWAP == 2) {
        const int lin = blockIdx.y * 8 + blockIdx.x;
        const int xcd = lin & 7;
        const int s   = lin >> 3;
        bn0 = (long)(s & 7) * BN;
        bm0 = (long)((s >> 3) * 8 + xcd) * BM;
    } else {
        bm0 = (long)(SWAP ? blockIdx.y : blockIdx.x) * BM;
        bn0 = (long)(SWAP ? blockIdx.x : blockIdx.y) * BN;
    }

    const bf16* Ause = A;
    const bf16* Buse = B;
    bf16* oz = outb;
    int  ldo = ldout;
    int  z   = 0;
    if (MODE == 0) {
        z = blockIdx.z;
        if (z == 2) {
            bm0  = (long)blockIdx.y * BM;
            bn0  = (long)blockIdx.x * BN;
            Ause = B + (size_t)2 * N * K;
            Buse = A;
            oz   = outb + (size_t)2 * M * ldout;
            ldo  = M;
        } else {
            Buse = B + (size_t)z * N * K;
            oz   = outb + (size_t)z * M * ldout;
        }
    }

    const int lrow = lane >> 2;
    const int lcol = (lane & 3) * 8;
    const bf16* gA[2][KH];
    const bf16* gB[2][KH];
    bf16* lA[2][KH];
    bf16* lB[2][KH];
#pragma unroll
    for (int u = 0; u < 2; u++)
#pragma unroll
        for (int h = 0; h < KH; h++) {
            gA[u][h] = Ause + (size_t)(bm0 + wave * 32 + u * 16 + lrow) * K + h * 32 + lcol;
            gB[u][h] = Buse + (size_t)(bn0 + wave * 32 + u * 16 + lrow) * ldb + h * 32 + lcol;
            lA[u][h] = As + h * TILE + (wave * 32 + u * 16) * 32;
            lB[u][h] = Bs + h * TILE + (wave * 32 + u * 16) * 32;
        }

    const bf16* Ard = As + (wm * 64 + l16) * 32 + quad * 8;
    const bf16* Brd = Bs + (wn * 64 + l16) * 32 + quad * 8;

    f32x4 acc[4][4];
    const f32x4 zero = {0.f, 0.f, 0.f, 0.f};
#pragma unroll
    for (int i = 0; i < 4; i++)
#pragma unroll
        for (int j = 0; j < 4; j++) acc[i][j] = zero;

    for (int k0 = 0; k0 < K; k0 += KH * 32) {
        __syncthreads();
#pragma unroll
        for (int u = 0; u < 2; u++)
#pragma unroll
            for (int h = 0; h < KH; h++) {
                gload_lds16(gA[u][h] + k0, lA[u][h]);
                gload_lds16(gB[u][h] + k0, lB[u][h]);
            }
        __syncthreads();
#pragma unroll
        for (int h = 0; h < KH; h++) {
            short8 af[4], bfr[4];
#pragma unroll
            for (int mi = 0; mi < 4; mi++)
                af[mi] = *reinterpret_cast<const short8*>(Ard + h * TILE + mi * 16 * 32);
#pragma unroll
            for (int ni = 0; ni < 4; ni++)
                bfr[ni] = *reinterpret_cast<const short8*>(Brd + h * TILE + ni * 16 * 32);
#pragma unroll
            for (int mi = 0; mi < 4; mi++)
#pragma unroll
                for (int ni = 0; ni < 4; ni++)
                    acc[mi][ni] = __builtin_amdgcn_mfma_f32_16x16x32_bf16(af[mi], bfr[ni], acc[mi][ni], 0, 0, 0);
        }
    }

    if (MODE == 0 || MODE == 1) {
        __syncthreads();
        float bcol[4];
        if (MODE == 0 && z < 2) {
            const float* bias = (z == 0) ? b0 : b1;
#pragma unroll
            for (int ni = 0; ni < 4; ni++) bcol[ni] = bias[bn0 + wn * 64 + l16 + ni * 16];
        }
#pragma unroll
        for (int mi = 0; mi < 4; mi++) {
            bf16* eb = smem + ((wave << 1) | (mi & 1)) * 1152;
#pragma unroll
            for (int r = 0; r < 4; r++) {
                float s = 0.f;
                float brow = 0.f;
                if (MODE == 0 && z == 2) brow = b2[bm0 + wm * 64 + mi * 16 + quad * 4 + r];
#pragma unroll
                for (int ni = 0; ni < 4; ni++) {
                    float v = acc[mi][ni][r];
                    if (MODE == 0) v += (z == 2) ? brow : bcol[ni];
                    else { v = __expf(v * scale); s += v; }
                    eb[(quad * 4 + r) * 72 + ni * 16 + l16] = __float2bfloat16(v);
                }
                if (MODE == 1) {
                    s += __shfl_xor(s, 1);
                    s += __shfl_xor(s, 2);
                    s += __shfl_xor(s, 4);
                    s += __shfl_xor(s, 8);
                    if (l16 == 0) atomicAdd(&lsum[bm0 + wm * 64 + mi * 16 + quad * 4 + r], s);
                }
            }
            asm volatile("s_waitcnt lgkmcnt(0)" ::: "memory");
#pragma unroll
            for (int p = 0; p < 2; p++) {
                int r2 = p * 8 + (lane >> 3);
                int c2 = (lane & 7) * 8;
                short8 val = *reinterpret_cast<const short8*>(eb + r2 * 72 + c2);
                *reinterpret_cast<short8*>(
                    oz + (size_t)(bm0 + wm * 64 + mi * 16 + r2) * ldo + bn0 + wn * 64 + c2) = val;
            }
        }
    } else {
        const int rb2 = wm * 64 + quad * 4;
        const int cb2 = wn * 64 + l16;
#pragma unroll
        for (int mi = 0; mi < 4; mi++)
#pragma unroll
            for (int r = 0; r < 4; r++) {
                long row = bm0 + rb2 + mi * 16 + r;
                float mul = (MODE == 3) ? 1.0f / lsum[row] : 0.f;
#pragma unroll
                for (int ni = 0; ni < 4; ni++) {
                    long col = bn0 + cb2 + ni * 16;
                    if (MODE == 3) outf[row * ldout + col] = acc[mi][ni][r] * mul;
                    else           outf[row * ldout + col] += acc[mi][ni][r];
                }
            }
    }
}

// ---------------------------------------------------------------------------
// gemm8v: PV = (P v^T)/lsum with a ring-3 counted-vmcnt pipeline.
// Regime match (corpus T3/T4): deep K (8192 -> T=128 tiles amortize the
// prologue), trivial epilogue, compute-bound.  256x128 tile, 512 thr/8 waves,
// per-wave out 64x64 (acc = 16 f32x4).  LDS: 3 slots x (256+128)x64 bf16
// = 144 KiB; stage 3 wave-gloads per phase into slot (u+2)%3 (dead since
// tile u-1's post-barrier); ONE vmcnt(6) per tile (= T_{u+2}'s 6 loads left
// in flight), vmcnt(0) only in the 2-tile tail.  A/B rows are 128 B; XOR
// chunk-swizzle (chunk ^= row&7) applied to the pre-swizzled GLOBAL source
// (gload_lds dest stays linear) and to the ds_read address (rule #21);
// residual conflict 2-way = free (m136).
// Grid dim3(8,32): xcd = lin&7, A row-slab (4 MB) L2-resident, reused 8x.
// ---------------------------------------------------------------------------
__global__ __launch_bounds__(512, 1)
void gemm8v(const bf16* __restrict__ A, const bf16* __restrict__ B,
            const float* __restrict__ lsum, float* __restrict__ outf,
            int K, int lda, int ldb, int ldout) {
    constexpr int SLOT = (256 + 128) * 64;   // 24576 elems = 48 KiB
    __shared__ __align__(16) bf16 smem[3 * SLOT];

    const int tid  = threadIdx.x;
    const int lane = tid & 63;
    const int w    = tid >> 6;      // 0..7
    const int wm   = w >> 1;        // 0..3 : 64-row block
    const int wn   = w & 1;         // 0..1 : 64-col block
    const int l16  = lane & 15;
    const int quad = lane >> 4;
    const int xr   = l16 & 7;

    const int lin = blockIdx.y * 8 + blockIdx.x;   // x fastest in dispatch
    const int xcd = lin & 7;
    const int s   = lin >> 3;
    const long bn0 = (long)(s & 7) * 128;
    const long bm0 = (long)((s >> 3) * 8 + xcd) * 256;

    // ---- staging: pre-swizzled global sources, linear LDS dests ----
    const int grow = lane >> 3;                 // row in 8-row group
    const int gcol = ((lane & 7) ^ grow) * 8;   // swizzled col chunk
    const bf16* gAsrc[4];
    const bf16* gBsrc[2];
    int ldsA[4], ldsB[2];
#pragma unroll
    for (int j = 0; j < 4; j++) {
        gAsrc[j] = A + (size_t)(bm0 + (w * 4 + j) * 8 + grow) * lda + gcol;
        ldsA[j]  = (w * 4 + j) * 8 * 64;
    }
#pragma unroll
    for (int j = 0; j < 2; j++) {
        gBsrc[j] = B + (size_t)(bn0 + (w * 2 + j) * 8 + grow) * ldb + gcol;
        ldsB[j]  = (256 + (w * 2 + j) * 8) * 64;
    }

    // ---- ds_read offsets (elems), same XOR on the read side ----
    int aoff[4][2], boff[4][2];
#pragma unroll
    for (int mi = 0; mi < 4; mi++)
#pragma unroll
        for (int ks = 0; ks < 2; ks++)
            aoff[mi][ks] = (wm * 64 + mi * 16 + l16) * 64 + (((ks * 4 + quad) ^ xr) * 8);
#pragma unroll
    for (int ni = 0; ni < 4; ni++)
#pragma unroll
        for (int ks = 0; ks < 2; ks++)
            boff[ni][ks] = (256 + wn * 64 + ni * 16 + l16) * 64 + (((ks * 4 + quad) ^ xr) * 8);

    f32x4 acc[4][4];
    const f32x4 zero = {0.f, 0.f, 0.f, 0.f};
#pragma unroll
    for (int i = 0; i < 4; i++)
#pragma unroll
        for (int j = 0; j < 4; j++) acc[i][j] = zero;

    auto stg = [&](bf16* dst, int u, int part) {
        size_t ko = (size_t)u * 64;
        if (part == 0) {
            gload_lds16(gAsrc[0] + ko, dst + ldsA[0]);
            gload_lds16(gAsrc[1] + ko, dst + ldsA[1]);
            gload_lds16(gBsrc[0] + ko, dst + ldsB[0]);
        } else {
            gload_lds16(gAsrc[2] + ko, dst + ldsA[2]);
            gload_lds16(gAsrc[3] + ko, dst + ldsA[3]);
            gload_lds16(gBsrc[1] + ko, dst + ldsB[1]);
        }
    };

    const int T = K / 64;
    // prologue: T0 -> slot0, T1 -> slot1 (6+6 loads); T0 ready at vmcnt(6)
    stg(smem, 0, 0);            stg(smem, 0, 1);
    stg(smem + SLOT, 1, 0);     stg(smem + SLOT, 1, 1);
    waitvm<6>();
    __builtin_amdgcn_s_barrier();

    int rs = 0;
    for (int u = 0; u < T; ++u) {
        const bf16* sl = smem + rs * SLOT;
        int ss = rs + 2; if (ss >= 3) ss -= 3;
        bf16* sdst = smem + ss * SLOT;
        const bool doStage = (u + 2 < T);

        short8 bfr[4][2];
#pragma unroll
        for (int ph = 0; ph < 2; ++ph) {
            short8 af[2][2];
            if (ph == 0) {
#pragma unroll
                for (int ni = 0; ni < 4; ni++)
#pragma unroll
                    for (int ks = 0; ks < 2; ks++)
                        bfr[ni][ks] = *reinterpret_cast<const short8*>(sl + boff[ni][ks]);
            }
#pragma unroll
            for (int j = 0; j < 2; j++)
#pragma unroll
                for (int ks = 0; ks < 2; ks++)
                    af[j][ks] = *reinterpret_cast<const short8*>(sl + aoff[ph * 2 + j][ks]);
            if (doStage) stg(sdst, u + 2, ph);
            if (ph == 1 && u + 1 < T) {
                if (doStage) waitvm<6>();
                else         waitvm<0>();
            }
            __builtin_amdgcn_s_barrier();
            asm volatile("s_waitcnt lgkmcnt(0)" ::: "memory");
            __builtin_amdgcn_sched_barrier(0);
            __builtin_amdgcn_s_setprio(1);
#pragma unroll
            for (int ks = 0; ks < 2; ks++)
#pragma unroll
                for (int j = 0; j < 2; j++)
#pragma unroll
                    for (int ni = 0; ni < 4; ni++)
                        acc[ph * 2 + j][ni] = __builtin_amdgcn_mfma_f32_16x16x32_bf16(
                            af[j][ks], bfr[ni][ks], acc[ph * 2 + j][ni], 0, 0, 0);
            __builtin_amdgcn_s_setprio(0);
            __builtin_amdgcn_s_barrier();
        }
        rs = (rs + 1 == 3) ? 0 : rs + 1;
    }

    // epilogue: out = acc / lsum[row]   (C/D layout m89/m91)
#pragma unroll
    for (int mi = 0; mi < 4; mi++)
#pragma unroll
        for (int r = 0; r < 4; r++) {
            long row = bm0 + wm * 64 + mi * 16 + quad * 4 + r;
            float mul = 1.0f / lsum[row];
#pragma unroll
            for (int ni = 0; ni < 4; ni++) {
                long col = bn0 + wn * 64 + ni * 16 + l16;
                outf[row * ldout + col] = acc[mi][ni][r] * mul;
            }
        }
}

extern "C" void kernel_launch(void* const* d_in, const int* in_sizes, int n_in,
                              void* d_out, int out_size, void* d_ws, size_t ws_size,
                              hipStream_t stream) {
    const float* feat = (const float*)d_in[0];
    const float* Wq   = (const float*)d_in[1];
    const float* bqv  = (const float*)d_in[2];
    const float* Wk   = (const float*)d_in[3];
    const float* bkv  = (const float*)d_in[4];
    const float* Wv   = (const float*)d_in[5];
    const float* bvv  = (const float*)d_in[6];
    float* outp = (float*)d_out;

    const int M = 8192, D = 1024;
    char* ws = (char*)d_ws;
    size_t off = 0;
    auto carve = [&](size_t bytes) -> char* {
        char* r = ws + off;
        off += (bytes + 255) & ~(size_t)255;
        return r;
    };
    bf16* featb = (bf16*)carve((size_t)M * D * 2);
    bf16* Wbt   = (bf16*)carve((size_t)3 * D * D * 2);
    bf16* qk    = (bf16*)carve((size_t)2 * M * D * 2 + (size_t)D * M * 2);
    bf16* vbt   = qk + (size_t)2 * M * D;
    float* lsum = (float*)carve((size_t)M * 4);
    size_t avail = (ws_size > off) ? ws_size - off : 0;

    int C;  // key-chunk width for P
    if      (avail >= (size_t)M * M * 2)    C = M;     // full P, 128 MB
    else if (avail >= (size_t)M * 4096 * 2) C = 4096;
    else if (avail >= (size_t)M * 2048 * 2) C = 2048;
    else                                    C = 1024;
    bf16* Pc = (bf16*)carve((size_t)M * C * 2);

    // 1) fused prep: feat->bf16, W transpose+cvt, lsum zero
    prep_kernel<<<dim3(11265), dim3(256), 0, stream>>>(
        feat, (unsigned short*)featb, Wq, Wk, Wv, Wbt, lsum);
    // 2) merged projection: z=0,1 -> q,k; z=2 -> v^T directly (BK=64)
    gemm_bt<0, 2, 0><<<dim3(M / 128, D / 128, 3), dim3(256), 0, stream>>>(
        featb, Wbt, bqv, bkv, bvv, nullptr, qk, nullptr, M, D, D, D, D, 1.0f);

    const float scale = 0.03125f;  // 1/sqrt(1024)
    bf16* qb = qk;
    bf16* kb = qk + (size_t)M * D;
    if (C == M) {
        // 3a) full P = exp(q k^T/32): proven baseline 128x128, grid 64x64
        gemm_bt<1, 2, 0><<<dim3(M / 128, M / 128), dim3(256), 0, stream>>>(
            qb, kb, nullptr, nullptr, nullptr, lsum, Pc, nullptr, M, M, D, D, M, scale);
        // 4a) out = (P v^T)/lsum: ring-3 counted-vmcnt pipeline, K=8192 deep
        gemm8v<<<dim3(8, 32), dim3(512), 0, stream>>>(
            Pc, vbt, lsum, outp, M, M, M, D);
    } else {
        hipMemsetAsync(outp, 0, (size_t)M * D * 4, stream);
        for (int c = 0; c < M / C; c++) {
            gemm_bt<1, 2, 0><<<dim3(M / 128, C / 128), dim3(256), 0, stream>>>(
                qb, kb + (size_t)c * C * D, nullptr, nullptr, nullptr, lsum, Pc, nullptr,
                M, C, D, D, C, scale);
            gemm_bt<2, 2, 1><<<dim3(D / 128, M / 128), dim3(256), 0, stream>>>(
                Pc, vbt + (size_t)c * C, nullptr, nullptr, nullptr, nullptr, nullptr, outp,
                M, D, C, M, D, 0.f);
        }
        scale_rows<<<dim3(M * D / 4 / 256), dim3(256), 0, stream>>>(outp, lsum);
    }
}